// Round 9
// baseline (367.861 us; speedup 1.0000x reference)
//
#include <hip/hip_runtime.h>

#define E_ 4032
#define TE 64
#define NB 4032  // 258048 / TE

typedef unsigned int uint;
typedef unsigned short ushort;
typedef __attribute__((ext_vector_type(8))) short short8;
typedef __attribute__((ext_vector_type(4))) float f32x4;
typedef __attribute__((ext_vector_type(2))) float f32x2;

__device__ __forceinline__ ushort f2bf(float x) {
  uint u = __float_as_uint(x);
  return (ushort)((u + 0x7fffu + ((u >> 16) & 1u)) >> 16);  // RNE f32->bf16
}
__device__ __forceinline__ uint cvtpk(float lo, float hi) {
  uint r;
  asm("v_cvt_pk_bf16_f32 %0, %1, %2" : "=v"(r) : "v"(lo), "v"(hi));
  return r;
}
__device__ __forceinline__ float exp2_(float x) {
  float r;
  asm("v_exp_f32 %0, %1" : "=v"(r) : "v"(x));
  return r;
}
__device__ __forceinline__ float bflo(uint u) { return __uint_as_float(u << 16); }
__device__ __forceinline__ float bfhi(uint u) { return __uint_as_float(u & 0xffff0000u); }
__device__ __forceinline__ float bf2f(ushort s) { return __uint_as_float((uint)s << 16); }
__device__ __forceinline__ float rcp_(float x) { return __builtin_amdgcn_rcpf(x); }
__device__ __forceinline__ float silu_(float v) { return v * rcp_(1.0f + exp2_(v * -1.44269504f)); }
__device__ __forceinline__ float sigmoid_(float v) { return rcp_(1.0f + exp2_(v * -1.44269504f)); }
__device__ __forceinline__ float tanh_(float v) { return 1.0f - 2.0f * rcp_(1.0f + exp2_(v * 2.88539008f)); }

__device__ __forceinline__ f32x2 silu2(f32x2 v) {
  f32x2 nm = v * (f32x2){-1.44269504f, -1.44269504f};
  f32x2 e = {exp2_(nm.x), exp2_(nm.y)};
  f32x2 den = e + (f32x2){1.0f, 1.0f};
  f32x2 r = {rcp_(den.x), rcp_(den.y)};
  return v * r;
}

__device__ __forceinline__ void atom_pk_bf16(ushort* p, uint v) {
  asm volatile("global_atomic_pk_add_bf16 %0, %1, off" :: "v"(p), "v"(v) : "memory");
}

// RM*16 x 256 (A, LDS, swizzled bf16) @ 256x256 (B = WT[n][k] bf16, L2) -> acc
// wave w owns cols [w*64, w*64+64)
template <int RM>
__device__ __forceinline__ void gemmT(const ushort* Ab, const ushort* Bmat,
                                      int w, int l15, int lhi, f32x4 acc[RM][4]) {
#pragma unroll
  for (int ks = 0; ks < 8; ++ks) {
    short8 bv[4];
#pragma unroll
    for (int cn = 0; cn < 4; ++cn) {
      int col = w * 64 + cn * 16 + l15;
      bv[cn] = *(const short8*)(Bmat + col * 256 + ks * 32 + lhi * 8);
    }
    short8 av[RM];
#pragma unroll
    for (int rm = 0; rm < RM; ++rm) {
      int row = rm * 16 + l15;
      int byt = (ks * 64 + lhi * 16) ^ ((row & 7) << 4);
      av[rm] = *(const short8*)((const char*)Ab + row * 512 + byt);
    }
#pragma unroll
    for (int cn = 0; cn < 4; ++cn)
#pragma unroll
      for (int rm = 0; rm < RM; ++rm)
        acc[rm][cn] = __builtin_amdgcn_mfma_f32_16x16x32_bf16(av[rm], bv[cn], acc[rm][cn], 0, 0, 0);
  }
}

// ---- fused: CSR count (1008 blocks) + weight transpose prep (144 blocks) ----
// WT[9][256][256] bf16, WT[m][n][k] = srcm[k*256 + n]
__global__ __launch_bounds__(256) void k_count_prep(
    const int* __restrict__ eidx, uint* __restrict__ cnt,
    const float* __restrict__ We1, const float* __restrict__ Wx1,
    const float* __restrict__ Wh1, const float* __restrict__ We2,
    const float* __restrict__ Wx2, const float* __restrict__ Wh2,
    ushort* __restrict__ WT) {
  __shared__ float tl[64][65];
  int bid = blockIdx.x;
  int t = threadIdx.x;
  if (bid < 1008) {
    int g = bid * 256 + t;
    int b = g / E_;
    int i = eidx[(size_t)g * 2];
    atomicAdd(&cnt[b * 64 + i], 1u);
    return;
  }
  int blk = bid - 1008;
  int m = blk >> 4, tile = blk & 15;
  int kt = (tile & 3) * 64, nt = (tile >> 2) * 64;
  const float* src;
  switch (m) {
    case 0: src = We1; break;
    case 1: src = We1 + 65536; break;
    case 2: src = Wx1; break;
    case 3: src = Wx1 + 65536; break;
    case 4: src = Wh1; break;
    case 5: src = We2; break;
    case 6: src = Wx2; break;
    case 7: src = Wh1 + 65536; break;
    default: src = Wh2; break;
  }
  int c = t & 63, r4 = t >> 6;
#pragma unroll
  for (int rr = 0; rr < 64; rr += 4)
    tl[rr + r4][c] = src[(size_t)(kt + rr + r4) * 256 + nt + c];
  __syncthreads();
#pragma unroll
  for (int rr = 0; rr < 64; rr += 4)
    WT[(size_t)m * 65536 + (size_t)(nt + rr + r4) * 256 + kt + c] = f2bf(tl[c][rr + r4]);
}

__global__ __launch_bounds__(256) void k_scan(const uint* __restrict__ cnt,
                                              uint* __restrict__ cursor) {
  __shared__ uint sw[4];
  int t = threadIdx.x;
  uint loc[16];
  uint tot = 0;
#pragma unroll
  for (int q = 0; q < 16; ++q) {
    loc[q] = cnt[t * 16 + q];
    tot += loc[q];
  }
  uint v = tot;  // inclusive scan within wave
#pragma unroll
  for (int d = 1; d < 64; d <<= 1) {
    uint u = __shfl_up(v, d);
    if ((t & 63) >= d) v += u;
  }
  if ((t & 63) == 63) sw[t >> 6] = v;
  __syncthreads();
  uint woff = 0;
  int wv = t >> 6;
  if (wv > 0) woff += sw[0];
  if (wv > 1) woff += sw[1];
  if (wv > 2) woff += sw[2];
  uint run = woff + v - tot;  // global exclusive prefix
#pragma unroll
  for (int q = 0; q < 16; ++q) {
    cursor[t * 16 + q] = run;
    run += loc[q];
  }
}

// ---- fused: CSR fill (1008 blocks) + projection GEMM (160 blocks) ----
// P[4096][1280] bf16 = h @ [We1L|We1R|Wx1L|Wx1R|Wh1top]
__global__ __launch_bounds__(256, 2) void k_fill_proj(
    const int* __restrict__ eidx, uint* __restrict__ cursor,
    uint* __restrict__ perm, const float* __restrict__ h,
    const ushort* __restrict__ WT, ushort* __restrict__ P) {
  __shared__ ushort Ab[128 * 256];
  int bid = blockIdx.x;
  int t = threadIdx.x;
  if (bid < 1008) {
    int g = bid * 256 + t;
    int b = g / E_;
    int i = eidx[(size_t)g * 2];
    uint slot = atomicAdd(&cursor[b * 64 + i], 1u);
    perm[slot] = (uint)g;
    return;
  }
  int blk = bid - 1008;
  int rowbase = (blk & 31) * 128;
  int g = blk >> 5;  // 0..4
  {
    int c2 = t & 127, es = t >> 7;
#pragma unroll 4
    for (int it = 0; it < 64; ++it) {
      int row = it * 2 + es;
      float2 v = *(const float2*)(h + (size_t)(rowbase + row) * 256 + c2 * 2);
      *(uint*)((char*)Ab + row * 512 + ((c2 * 4) ^ ((row & 7) << 4))) = cvtpk(v.x, v.y);
    }
  }
  __syncthreads();
  int w = t >> 6, lane = t & 63, l15 = lane & 15, lhi = lane >> 4;
  f32x4 acc[8][4] = {};
  gemmT<8>(Ab, WT + g * 65536, w, l15, lhi, acc);
#pragma unroll
  for (int rm = 0; rm < 8; ++rm)
#pragma unroll
    for (int cn = 0; cn < 4; ++cn)
#pragma unroll
      for (int r = 0; r < 4; ++r) {
        int row = rowbase + rm * 16 + lhi * 4 + r;
        int col = w * 64 + cn * 16 + l15;
        P[(size_t)row * 1280 + g * 256 + col] = f2bf(acc[rm][cn][r]);
      }
}

// build T1 = silu(P_i + P_j + d2*w512 + a@Wrows + b1) into swizzled LDS tile
__device__ __forceinline__ void buildT1(int t, const uint* __restrict__ Pu,
                                        const float* __restrict__ Wbig,
                                        const float* __restrict__ b1, int offI,
                                        ushort* Ab, const uint* s_pio,
                                        const uint* s_pjo,
                                        const float* s_d2, const float4* s_a4) {
  int c2 = t & 63, es = t >> 6;  // c2: uint2 index -> cols c2*4..c2*4+3
  int c0 = c2 * 4;
  const float* Wr = Wbig + 512 * 256 + c0;
  f32x2 w5A = *(const f32x2*)(Wr);        f32x2 w5B = *(const f32x2*)(Wr + 2);
  f32x2 a0A = *(const f32x2*)(Wr + 256);  f32x2 a0B = *(const f32x2*)(Wr + 258);
  f32x2 a1A = *(const f32x2*)(Wr + 512);  f32x2 a1B = *(const f32x2*)(Wr + 514);
  f32x2 a2A = *(const f32x2*)(Wr + 768);  f32x2 a2B = *(const f32x2*)(Wr + 770);
  f32x2 a3A = *(const f32x2*)(Wr + 1024); f32x2 a3B = *(const f32x2*)(Wr + 1026);
  f32x2 bbA = *(const f32x2*)(b1 + c0);   f32x2 bbB = *(const f32x2*)(b1 + c0 + 2);
  const uint* Pme = Pu + (uint)(offI + c2 * 2);
  const uint* Pmj = Pu + (uint)(offI + 128 + c2 * 2);
#pragma unroll
  for (int it = 0; it < 16; ++it) {
    int e = it * 4 + es;
    uint2 pi = *(const uint2*)(Pme + s_pio[e]);
    uint2 pj = *(const uint2*)(Pmj + s_pjo[e]);
    f32x2 d2v;
    d2v.x = s_d2[e];
    d2v.y = d2v.x;
    float4 av = s_a4[e];
    f32x2 vA = (f32x2){bflo(pi.x), bfhi(pi.x)} + (f32x2){bflo(pj.x), bfhi(pj.x)};
    f32x2 vB = (f32x2){bflo(pi.y), bfhi(pi.y)} + (f32x2){bflo(pj.y), bfhi(pj.y)};
    f32x2 axv = {av.x, av.x}, ayv = {av.y, av.y}, azv = {av.z, av.z}, awv = {av.w, av.w};
    f32x2 zA = bbA + d2v * w5A + axv * a0A + ayv * a1A + azv * a2A + awv * a3A;
    f32x2 zB = bbB + d2v * w5B + axv * a0B + ayv * a1B + azv * a2B + awv * a3B;
    vA = silu2(vA + zA);
    vB = silu2(vB + zB);
    uint2 o;
    o.x = cvtpk(vA.x, vA.y);
    o.y = cvtpk(vB.x, vB.y);
    *(uint2*)((char*)Ab + e * 512 + ((c0 * 2) ^ ((e & 7) << 4))) = o;
  }
}

// monolithic edge kernel (R5 semantics) with build0 reg-staged under gemm1
__global__ __launch_bounds__(256, 4) void k_edge(
    const float* __restrict__ x, const int* __restrict__ eidx,
    const float* __restrict__ a, const float* __restrict__ emask,
    const uint* __restrict__ perm,
    const ushort* __restrict__ P, const ushort* __restrict__ WT,
    const float* __restrict__ We1, const float* __restrict__ be1,
    const float* __restrict__ be2, const float* __restrict__ Wa,
    const float* __restrict__ ba,
    const float* __restrict__ Wx1, const float* __restrict__ bx1,
    const float* __restrict__ bx2, const float* __restrict__ Wx3,
    ushort* __restrict__ em_agg, float* __restrict__ x_agg) {
  __shared__ ushort Ab[TE * 256];  // 32 KiB swizzled T1 tile / em staging
  __shared__ uint s_ij[TE];        // i4 | (j4<<16), sorted by i4
  __shared__ uint s_pio[TE], s_pjo[TE];  // P row offsets (uint idx)
  __shared__ float s_d2[TE];
  __shared__ float4 s_a4[TE];
  __shared__ float s_dx[TE], s_dy[TE], s_dz[TE];
  __shared__ float s_red[2][TE];
  __shared__ ushort s_seghead[TE + 2];
  __shared__ int s_nseg;
  int t = threadIdx.x;
  int bid = blockIdx.x;
  bid = (bid & 7) * 504 + (bid >> 3);  // XCD swizzle (4032 = 8*504)
  int ebase = bid * TE;                // sorted slots; one batch per block

  if (t < TE) {  // phase 0: edge meta (CSR-sorted gather) -- exactly wave 0
    int eid = (int)perm[ebase + t];
    int b = ebase / E_;
    int2 ij = *(const int2*)(eidx + (size_t)eid * 2);
    uint i4 = (uint)(b * 64 + ij.x);
    uint j4 = (uint)(b * 64 + ij.y);
    s_ij[t] = i4 | (j4 << 16);
    s_pio[t] = i4 * 640u;
    s_pjo[t] = j4 * 640u;
    float m = emask[eid];
    float dx = (x[i4 * 3 + 0] - x[j4 * 3 + 0]) * m;
    float dy = (x[i4 * 3 + 1] - x[j4 * 3 + 1]) * m;
    float dz = (x[i4 * 3 + 2] - x[j4 * 3 + 2]) * m;
    s_d2[t] = dx * dx + dy * dy + dz * dz;
    s_dx[t] = dx; s_dy[t] = dy; s_dz[t] = dz;
    s_a4[t] = *(const float4*)(a + (size_t)eid * 4);
    s_red[0][t] = 0.f;
    s_red[1][t] = 0.f;
    // segment heads via wave ballot (no serial scan)
    uint prev = __shfl_up(i4, 1);
    int flag = (t == 0) || (i4 != prev);
    unsigned long long mask = __ballot(flag);
    int rank = (int)__popcll(mask & ((1ull << t) - 1ull));
    if (flag) s_seghead[rank] = (ushort)t;
    if (t == 0) {
      int ns = (int)__popcll(mask);
      s_nseg = ns;
      s_seghead[ns] = TE;
    }
  }
  __syncthreads();

  const uint* Pu = (const uint*)P;
  int w = t >> 6, lane = t & 63, l15 = lane & 15, lhi = lane >> 4;
  float ba0 = ba[0];

  // ---- branch 1 build (x/Wx2) ----
  buildT1(t, Pu, Wx1, bx1, 256, Ab, s_pio, s_pjo, s_d2, s_a4);
  __syncthreads();

  // ---- stage branch-0 half-1 P-gathers BEFORE gemm1 (latency hides) ----
  int c2 = t & 63, es4 = t >> 6;
  int c0 = c2 * 4;
  const uint* Pme0 = Pu + (uint)(c2 * 2);
  const uint* Pmj0 = Pu + (uint)(128 + c2 * 2);
  uint2 pis[8], pjs[8];
#pragma unroll
  for (int it = 0; it < 8; ++it) {
    int e = it * 4 + es4;
    pis[it] = *(const uint2*)(Pme0 + s_pio[e]);
    pjs[it] = *(const uint2*)(Pmj0 + s_pjo[e]);
  }

  // ---- branch 1 gemm ----
  f32x4 acc1[4][4] = {};
  gemmT<4>(Ab, WT + 6 * 65536, w, l15, lhi, acc1);

  // ---- branch-0 build weights (loaded post-gemm to bound VGPR peak) ----
  const float* Wr0 = We1 + 512 * 256 + c0;
  f32x2 w5A = *(const f32x2*)(Wr0);        f32x2 w5B = *(const f32x2*)(Wr0 + 2);
  f32x2 a0A = *(const f32x2*)(Wr0 + 256);  f32x2 a0B = *(const f32x2*)(Wr0 + 258);
  f32x2 a1A = *(const f32x2*)(Wr0 + 512);  f32x2 a1B = *(const f32x2*)(Wr0 + 514);
  f32x2 a2A = *(const f32x2*)(Wr0 + 768);  f32x2 a2B = *(const f32x2*)(Wr0 + 770);
  f32x2 a3A = *(const f32x2*)(Wr0 + 1024); f32x2 a3B = *(const f32x2*)(Wr0 + 1026);
  f32x2 bbA = *(const f32x2*)(be1 + c0);   f32x2 bbB = *(const f32x2*)(be1 + c0 + 2);

  uint2 o0[16];
#pragma unroll
  for (int it = 0; it < 8; ++it) {  // compute half-1
    int e = it * 4 + es4;
    f32x2 d2v; d2v.x = s_d2[e]; d2v.y = d2v.x;
    float4 av = s_a4[e];
    f32x2 vA = (f32x2){bflo(pis[it].x), bfhi(pis[it].x)} + (f32x2){bflo(pjs[it].x), bfhi(pjs[it].x)};
    f32x2 vB = (f32x2){bflo(pis[it].y), bfhi(pis[it].y)} + (f32x2){bflo(pjs[it].y), bfhi(pjs[it].y)};
    f32x2 axv = {av.x, av.x}, ayv = {av.y, av.y}, azv = {av.z, av.z}, awv = {av.w, av.w};
    f32x2 zA = bbA + d2v * w5A + axv * a0A + ayv * a1A + azv * a2A + awv * a3A;
    f32x2 zB = bbB + d2v * w5B + axv * a0B + ayv * a1B + azv * a2B + awv * a3B;
    vA = silu2(vA + zA);
    vB = silu2(vB + zB);
    o0[it].x = cvtpk(vA.x, vA.y);
    o0[it].y = cvtpk(vB.x, vB.y);
  }
#pragma unroll
  for (int it = 8; it < 16; ++it) {  // issue half-2 gathers (hide under epi1)
    int e = it * 4 + es4;
    pis[it - 8] = *(const uint2*)(Pme0 + s_pio[e]);
    pjs[it - 8] = *(const uint2*)(Pmj0 + s_pjo[e]);
  }

  {  // epilogue branch 1: m = silu(acc+b2); row-dot -> s_red[1]
    int colb = w * 64 + l15;
    f32x2 wvA = {Wx3[colb], Wx3[colb + 16]};
    f32x2 wvB = {Wx3[colb + 32], Wx3[colb + 48]};
    f32x2 b2A = {bx2[colb], bx2[colb + 16]};
    f32x2 b2B = {bx2[colb + 32], bx2[colb + 48]};
#pragma unroll
    for (int rm = 0; rm < 4; ++rm)
#pragma unroll
      for (int r = 0; r < 4; ++r) {
        f32x2 mA = silu2((f32x2){acc1[rm][0][r], acc1[rm][1][r]} + b2A);
        f32x2 mB = silu2((f32x2){acc1[rm][2][r], acc1[rm][3][r]} + b2B);
        f32x2 q = mA * wvA + mB * wvB;
        float p = q.x + q.y;
        p += __shfl_xor(p, 1);
        p += __shfl_xor(p, 2);
        p += __shfl_xor(p, 4);
        p += __shfl_xor(p, 8);
        if (l15 == 0) atomicAdd(&s_red[1][rm * 16 + lhi * 4 + r], p);
      }
  }

#pragma unroll
  for (int it = 8; it < 16; ++it) {  // compute half-2
    int e = it * 4 + es4;
    f32x2 d2v; d2v.x = s_d2[e]; d2v.y = d2v.x;
    float4 av = s_a4[e];
    f32x2 vA = (f32x2){bflo(pis[it - 8].x), bfhi(pis[it - 8].x)} + (f32x2){bflo(pjs[it - 8].x), bfhi(pjs[it - 8].x)};
    f32x2 vB = (f32x2){bflo(pis[it - 8].y), bfhi(pis[it - 8].y)} + (f32x2){bflo(pjs[it - 8].y), bfhi(pjs[it - 8].y)};
    f32x2 axv = {av.x, av.x}, ayv = {av.y, av.y}, azv = {av.z, av.z}, awv = {av.w, av.w};
    f32x2 zA = bbA + d2v * w5A + axv * a0A + ayv * a1A + azv * a2A + awv * a3A;
    f32x2 zB = bbB + d2v * w5B + axv * a0B + ayv * a1B + azv * a2B + awv * a3B;
    vA = silu2(vA + zA);
    vB = silu2(vB + zB);
    o0[it].x = cvtpk(vA.x, vA.y);
    o0[it].y = cvtpk(vB.x, vB.y);
  }
  __syncthreads();  // s_red[1] final; all gemm1 Ab reads done -> Ab free

  // ---- commit staged branch-0 tile to LDS ----
#pragma unroll
  for (int it = 0; it < 16; ++it) {
    int e = it * 4 + es4;
    *(uint2*)((char*)Ab + e * 512 + ((c0 * 2) ^ ((e & 7) << 4))) = o0[it];
  }

  // ---- x_agg: wave-assigned segments (atomics drain under gemm0) ----
  {
    int ns = s_nseg;
    for (int s = w; s < ns; s += 4) {
      int st = s_seghead[s], en = s_seghead[s + 1];
      int r = st + lane;
      float sx = 0.f, sy = 0.f, sz = 0.f;
      if (r < en) {
        float fac = tanh_(s_red[1][r]) * 15.0f * rcp_(sqrtf(s_d2[r]) + 1.0f);
        sx = fac * s_dx[r]; sy = fac * s_dy[r]; sz = fac * s_dz[r];
      }
#pragma unroll
      for (int d = 1; d < 64; d <<= 1) {
        sx += __shfl_xor(sx, d);
        sy += __shfl_xor(sy, d);
        sz += __shfl_xor(sz, d);
      }
      if (lane == 0) {
        uint i4 = s_ij[st] & 0xffffu;
        atomicAdd(x_agg + i4 * 3u + 0, sx);
        atomicAdd(x_agg + i4 * 3u + 1, sy);
        atomicAdd(x_agg + i4 * 3u + 2, sz);
      }
    }
  }
  __syncthreads();  // Ab (branch-0 tile) visible to all waves

  // ---- branch 0 gemm + epilogue ----
  f32x4 acc0[4][4] = {};
  gemmT<4>(Ab, WT + 5 * 65536, w, l15, lhi, acc0);
  {
    int colb = w * 64 + l15;
    f32x2 wvA = {Wa[colb], Wa[colb + 16]};
    f32x2 wvB = {Wa[colb + 32], Wa[colb + 48]};
    f32x2 b2A = {be2[colb], be2[colb + 16]};
    f32x2 b2B = {be2[colb + 32], be2[colb + 48]};
#pragma unroll
    for (int rm = 0; rm < 4; ++rm)
#pragma unroll
      for (int r = 0; r < 4; ++r) {
        f32x2 mA = silu2((f32x2){acc0[rm][0][r], acc0[rm][1][r]} + b2A);
        f32x2 mB = silu2((f32x2){acc0[rm][2][r], acc0[rm][3][r]} + b2B);
        acc0[rm][0][r] = mA.x; acc0[rm][1][r] = mA.y;
        acc0[rm][2][r] = mB.x; acc0[rm][3][r] = mB.y;
        f32x2 q = mA * wvA + mB * wvB;
        float p = q.x + q.y;
        p += __shfl_xor(p, 1);
        p += __shfl_xor(p, 2);
        p += __shfl_xor(p, 4);
        p += __shfl_xor(p, 8);
        if (l15 == 0) atomicAdd(&s_red[0][rm * 16 + lhi * 4 + r], p);
      }
  }
  __syncthreads();  // s_red[0] final; Ab free (gemm0 reads done)

  // ---- gate (per-thread recompute: race-free) + dump m rows to Ab ----
  uint* AbU = (uint*)Ab;
#pragma unroll
  for (int rm = 0; rm < 4; ++rm)
#pragma unroll
    for (int r = 0; r < 4; ++r) {
      int row = rm * 16 + lhi * 4 + r;
      float g = sigmoid_(s_red[0][row] + ba0);
#pragma unroll
      for (int cn = 0; cn < 4; ++cn) {
        float vme = g * acc0[rm][cn][r];
        float vpo = __shfl_xor(vme, 1);
        if (!(l15 & 1)) {
          int cp = (w * 64 + cn * 16 + l15) >> 1;
          AbU[row * 128 + cp] = cvtpk(vme, vpo);
        }
      }
    }
  __syncthreads();

  // ---- segmented em reduction: fp32 sum over rows, 1 pk atomic per (seg,colpair)
  {
    int ns = s_nseg;
    int c = t & 127;
    for (int s = t >> 7; s < ns; s += 2) {
      int st = s_seghead[s], en = s_seghead[s + 1];
      f32x2 sum = {0.f, 0.f};
      for (int r = st; r < en; ++r) {
        uint u = AbU[r * 128 + c];
        sum += (f32x2){bflo(u), bfhi(u)};
      }
      uint i4 = s_ij[st] & 0xffffu;
      atom_pk_bf16(em_agg + i4 * 256u + (uint)(c * 2), cvtpk(sum.x, sum.y));
    }
  }
}

__global__ __launch_bounds__(256, 2) void k_node(
    const float* __restrict__ h, const float* __restrict__ x,
    const float* __restrict__ nmask,
    const ushort* __restrict__ em_agg, const float* __restrict__ x_agg,
    const ushort* __restrict__ P, const ushort* __restrict__ WT,
    const float* __restrict__ bh1, const float* __restrict__ bh2,
    float* __restrict__ out) {
  __shared__ ushort Ab[32 * 256];
  int t = threadIdx.x;
  int rowbase = blockIdx.x * 32;  // 128 blocks
  {  // stage em (bf16) into swizzled LDS
    const uint* emu = (const uint*)em_agg;
    int c2 = t & 127, es = t >> 7;
#pragma unroll 4
    for (int it = 0; it < 16; ++it) {
      int row = it * 2 + es;
      uint v = emu[(size_t)(rowbase + row) * 128 + c2];
      *(uint*)((char*)Ab + row * 512 + ((c2 * 4) ^ ((row & 7) << 4))) = v;
    }
  }
  __syncthreads();
  int w = t >> 6, lane = t & 63, l15 = lane & 15, lhi = lane >> 4;
  {
    f32x4 acc[2][4] = {};
    gemmT<2>(Ab, WT + 7 * 65536, w, l15, lhi, acc);  // em_agg @ Wh1bot
    __syncthreads();
    float bc[4];
#pragma unroll
    for (int cn = 0; cn < 4; ++cn) bc[cn] = bh1[w * 64 + cn * 16 + l15];
#pragma unroll
    for (int rm = 0; rm < 2; ++rm)
#pragma unroll
      for (int cn = 0; cn < 4; ++cn)
#pragma unroll
        for (int r = 0; r < 4; ++r) {
          int row = rm * 16 + lhi * 4 + r;
          int col = w * 64 + cn * 16 + l15;
          float q1 = bf2f(P[(size_t)(rowbase + row) * 1280 + 1024 + col]);  // h@Wh1top
          float sv = silu_(acc[rm][cn][r] + q1 + bc[cn]);
          *(ushort*)((char*)Ab + row * 512 + ((col * 2) ^ ((row & 7) << 4))) = f2bf(sv);
        }
  }
  __syncthreads();
  {
    f32x4 acc[2][4] = {};
    gemmT<2>(Ab, WT + 8 * 65536, w, l15, lhi, acc);  // silu(...) @ Wh2
    float bc[4];
#pragma unroll
    for (int cn = 0; cn < 4; ++cn) bc[cn] = bh2[w * 64 + cn * 16 + l15];
#pragma unroll
    for (int rm = 0; rm < 2; ++rm)
#pragma unroll
      for (int cn = 0; cn < 4; ++cn)
#pragma unroll
        for (int r = 0; r < 4; ++r) {
          int row = rowbase + rm * 16 + lhi * 4 + r;
          int col = w * 64 + cn * 16 + l15;
          float o = (h[(size_t)row * 256 + col] + acc[rm][cn][r] + bc[cn]) * nmask[row];
          out[12288 + (size_t)row * 256 + col] = o;
        }
  }
  if (t < 32) {  // x_out
    int row = rowbase + t;
    float nm = nmask[row];
#pragma unroll
    for (int c = 0; c < 3; ++c)
      out[row * 3 + c] = (x[row * 3 + c] + x_agg[row * 3 + c]) * nm;
  }
}

extern "C" void kernel_launch(void* const* d_in, const int* in_sizes, int n_in,
                              void* d_out, int out_size, void* d_ws, size_t ws_size,
                              hipStream_t stream) {
  (void)in_sizes; (void)n_in; (void)out_size; (void)ws_size;
  const float* x = (const float*)d_in[0];
  const float* h = (const float*)d_in[1];
  const float* a = (const float*)d_in[2];
  const int* eidx = (const int*)d_in[3];
  const float* nmask = (const float*)d_in[4];
  const float* emask = (const float*)d_in[5];
  const float* We1 = (const float*)d_in[6];
  const float* be1 = (const float*)d_in[7];
  const float* We2 = (const float*)d_in[8];
  const float* be2 = (const float*)d_in[9];
  const float* Wa = (const float*)d_in[10];
  const float* ba = (const float*)d_in[11];
  const float* Wh1 = (const float*)d_in[12];
  const float* bh1 = (const float*)d_in[13];
  const float* Wh2 = (const float*)d_in[14];
  const float* bh2 = (const float*)d_in[15];
  const float* Wx1 = (const float*)d_in[16];
  const float* bx1 = (const float*)d_in[17];
  const float* Wx2 = (const float*)d_in[18];
  const float* bx2 = (const float*)d_in[19];
  const float* Wx3 = (const float*)d_in[20];

  char* ws = (char*)d_ws;
  ushort* WT = (ushort*)ws;                   // 9*65536*2   = 1,179,648 B
  ushort* P = (ushort*)(ws + 1179648);        // 4096*1280*2 = 10,485,760 B
  ushort* em_agg = (ushort*)(ws + 11665408);  // 4096*256*2  = 2,097,152 B
  float* x_agg = (float*)(ws + 13762560);     // 4096*3*4    = 49,152 B
  uint* cnt = (uint*)(ws + 13811712);         // 4096*4      = 16,384 B
  uint* cursor = (uint*)(ws + 13828096);      // 4096*4      = 16,384 B
  uint* perm = (uint*)(ws + 13844480);        // 258048*4    = 1,032,192 B

  // zero em_agg + x_agg + cnt (contiguous)
  hipMemsetAsync(em_agg, 0, 2097152 + 49152 + 16384, stream);
  k_count_prep<<<1152, 256, 0, stream>>>(eidx, cnt, We1, Wx1, Wh1, We2, Wx2, Wh2, WT);
  k_scan<<<1, 256, 0, stream>>>(cnt, cursor);
  k_fill_proj<<<1168, 256, 0, stream>>>(eidx, cursor, perm, h, WT, P);
  k_edge<<<NB, 256, 0, stream>>>(x, eidx, a, emask, perm, P, WT, We1, be1, be2, Wa, ba,
                                 Wx1, bx1, bx2, Wx3, em_agg, x_agg);
  k_node<<<128, 256, 0, stream>>>(h, x, nmask, em_agg, x_agg, P, WT, bh1, bh2,
                                  (float*)d_out);
}

// Round 10
// 272.324 us; speedup vs baseline: 1.3508x; 1.3508x over previous
//
#include <hip/hip_runtime.h>

#define E_ 4032
#define TE 64
#define NB 4032  // 258048 / TE

typedef unsigned int uint;
typedef unsigned short ushort;
typedef __attribute__((ext_vector_type(8))) short short8;
typedef __attribute__((ext_vector_type(4))) float f32x4;
typedef __attribute__((ext_vector_type(2))) float f32x2;

__device__ __forceinline__ ushort f2bf(float x) {
  uint u = __float_as_uint(x);
  return (ushort)((u + 0x7fffu + ((u >> 16) & 1u)) >> 16);  // RNE f32->bf16
}
__device__ __forceinline__ uint cvtpk(float lo, float hi) {
  uint r;
  asm("v_cvt_pk_bf16_f32 %0, %1, %2" : "=v"(r) : "v"(lo), "v"(hi));
  return r;
}
__device__ __forceinline__ float exp2_(float x) {
  float r;
  asm("v_exp_f32 %0, %1" : "=v"(r) : "v"(x));
  return r;
}
__device__ __forceinline__ float bflo(uint u) { return __uint_as_float(u << 16); }
__device__ __forceinline__ float bfhi(uint u) { return __uint_as_float(u & 0xffff0000u); }
__device__ __forceinline__ float bf2f(ushort s) { return __uint_as_float((uint)s << 16); }
__device__ __forceinline__ float rcp_(float x) { return __builtin_amdgcn_rcpf(x); }
__device__ __forceinline__ float silu_(float v) { return v * rcp_(1.0f + exp2_(v * -1.44269504f)); }
__device__ __forceinline__ float sigmoid_(float v) { return rcp_(1.0f + exp2_(v * -1.44269504f)); }
__device__ __forceinline__ float tanh_(float v) { return 1.0f - 2.0f * rcp_(1.0f + exp2_(v * 2.88539008f)); }

__device__ __forceinline__ f32x2 silu2(f32x2 v) {
  f32x2 nm = v * (f32x2){-1.44269504f, -1.44269504f};
  f32x2 e = {exp2_(nm.x), exp2_(nm.y)};
  f32x2 den = e + (f32x2){1.0f, 1.0f};
  f32x2 r = {rcp_(den.x), rcp_(den.y)};
  return v * r;
}

__device__ __forceinline__ void atom_pk_bf16(ushort* p, uint v) {
  asm volatile("global_atomic_pk_add_bf16 %0, %1, off" :: "v"(p), "v"(v) : "memory");
}

// RM*16 x 256 (A, LDS, swizzled bf16) @ 256x256 (B = WT[n][k] bf16, L2) -> acc
// wave w owns cols [w*64, w*64+64)
template <int RM>
__device__ __forceinline__ void gemmT(const ushort* Ab, const ushort* Bmat,
                                      int w, int l15, int lhi, f32x4 acc[RM][4]) {
#pragma unroll
  for (int ks = 0; ks < 8; ++ks) {
    short8 bv[4];
#pragma unroll
    for (int cn = 0; cn < 4; ++cn) {
      int col = w * 64 + cn * 16 + l15;
      bv[cn] = *(const short8*)(Bmat + col * 256 + ks * 32 + lhi * 8);
    }
    short8 av[RM];
#pragma unroll
    for (int rm = 0; rm < RM; ++rm) {
      int row = rm * 16 + l15;
      int byt = (ks * 64 + lhi * 16) ^ ((row & 7) << 4);
      av[rm] = *(const short8*)((const char*)Ab + row * 512 + byt);
    }
#pragma unroll
    for (int cn = 0; cn < 4; ++cn)
#pragma unroll
      for (int rm = 0; rm < RM; ++rm)
        acc[rm][cn] = __builtin_amdgcn_mfma_f32_16x16x32_bf16(av[rm], bv[cn], acc[rm][cn], 0, 0, 0);
  }
}

// ---- fused: CSR count (1008 blocks) + weight transpose prep (144 blocks) ----
// WT[9][256][256] bf16, WT[m][n][k] = srcm[k*256 + n]
__global__ __launch_bounds__(256) void k_count_prep(
    const int* __restrict__ eidx, uint* __restrict__ cnt,
    const float* __restrict__ We1, const float* __restrict__ Wx1,
    const float* __restrict__ Wh1, const float* __restrict__ We2,
    const float* __restrict__ Wx2, const float* __restrict__ Wh2,
    ushort* __restrict__ WT) {
  __shared__ float tl[64][65];
  int bid = blockIdx.x;
  int t = threadIdx.x;
  if (bid < 1008) {
    int g = bid * 256 + t;
    int b = g / E_;
    int i = eidx[(size_t)g * 2];
    atomicAdd(&cnt[b * 64 + i], 1u);
    return;
  }
  int blk = bid - 1008;
  int m = blk >> 4, tile = blk & 15;
  int kt = (tile & 3) * 64, nt = (tile >> 2) * 64;
  const float* src;
  switch (m) {
    case 0: src = We1; break;
    case 1: src = We1 + 65536; break;
    case 2: src = Wx1; break;
    case 3: src = Wx1 + 65536; break;
    case 4: src = Wh1; break;
    case 5: src = We2; break;
    case 6: src = Wx2; break;
    case 7: src = Wh1 + 65536; break;
    default: src = Wh2; break;
  }
  int c = t & 63, r4 = t >> 6;
#pragma unroll
  for (int rr = 0; rr < 64; rr += 4)
    tl[rr + r4][c] = src[(size_t)(kt + rr + r4) * 256 + nt + c];
  __syncthreads();
#pragma unroll
  for (int rr = 0; rr < 64; rr += 4)
    WT[(size_t)m * 65536 + (size_t)(nt + rr + r4) * 256 + kt + c] = f2bf(tl[c][rr + r4]);
}

__global__ __launch_bounds__(256) void k_scan(const uint* __restrict__ cnt,
                                              uint* __restrict__ cursor) {
  __shared__ uint sw[4];
  int t = threadIdx.x;
  uint loc[16];
  uint tot = 0;
#pragma unroll
  for (int q = 0; q < 16; ++q) {
    loc[q] = cnt[t * 16 + q];
    tot += loc[q];
  }
  uint v = tot;  // inclusive scan within wave
#pragma unroll
  for (int d = 1; d < 64; d <<= 1) {
    uint u = __shfl_up(v, d);
    if ((t & 63) >= d) v += u;
  }
  if ((t & 63) == 63) sw[t >> 6] = v;
  __syncthreads();
  uint woff = 0;
  int wv = t >> 6;
  if (wv > 0) woff += sw[0];
  if (wv > 1) woff += sw[1];
  if (wv > 2) woff += sw[2];
  uint run = woff + v - tot;  // global exclusive prefix
#pragma unroll
  for (int q = 0; q < 16; ++q) {
    cursor[t * 16 + q] = run;
    run += loc[q];
  }
}

// ---- fused: CSR fill (1008 blocks) + projection GEMM (160 blocks) ----
// P[4096][1280] bf16 = h @ [We1L|We1R|Wx1L|Wx1R|Wh1top]
__global__ __launch_bounds__(256, 2) void k_fill_proj(
    const int* __restrict__ eidx, uint* __restrict__ cursor,
    uint* __restrict__ perm, const float* __restrict__ h,
    const ushort* __restrict__ WT, ushort* __restrict__ P) {
  __shared__ ushort Ab[128 * 256];
  int bid = blockIdx.x;
  int t = threadIdx.x;
  if (bid < 1008) {
    int g = bid * 256 + t;
    int b = g / E_;
    int i = eidx[(size_t)g * 2];
    uint slot = atomicAdd(&cursor[b * 64 + i], 1u);
    perm[slot] = (uint)g;
    return;
  }
  int blk = bid - 1008;
  int rowbase = (blk & 31) * 128;
  int g = blk >> 5;  // 0..4
  {
    int c2 = t & 127, es = t >> 7;
#pragma unroll 4
    for (int it = 0; it < 64; ++it) {
      int row = it * 2 + es;
      float2 v = *(const float2*)(h + (size_t)(rowbase + row) * 256 + c2 * 2);
      *(uint*)((char*)Ab + row * 512 + ((c2 * 4) ^ ((row & 7) << 4))) = cvtpk(v.x, v.y);
    }
  }
  __syncthreads();
  int w = t >> 6, lane = t & 63, l15 = lane & 15, lhi = lane >> 4;
  f32x4 acc[8][4] = {};
  gemmT<8>(Ab, WT + g * 65536, w, l15, lhi, acc);
#pragma unroll
  for (int rm = 0; rm < 8; ++rm)
#pragma unroll
    for (int cn = 0; cn < 4; ++cn)
#pragma unroll
      for (int r = 0; r < 4; ++r) {
        int row = rowbase + rm * 16 + lhi * 4 + r;
        int col = w * 64 + cn * 16 + l15;
        P[(size_t)row * 1280 + g * 256 + col] = f2bf(acc[rm][cn][r]);
      }
}

// build T1 = silu(P_i + P_j + d2*w512 + a@Wrows + b1) into swizzled LDS tile
// unroll 2 (NOT full): keeps in-flight gather state at 4 uint2 -> no scratch
// spill (R4: FETCH 18.7MB; R5 full-unroll: FETCH 61MB, WRITE +70MB scratch).
__device__ __forceinline__ void buildT1(int t, const uint* __restrict__ Pu,
                                        const float* __restrict__ Wbig,
                                        const float* __restrict__ b1, int offI,
                                        ushort* Ab, const uint* s_pio,
                                        const uint* s_pjo,
                                        const float* s_d2, const float4* s_a4) {
  int c2 = t & 63, es = t >> 6;  // c2: uint2 index -> cols c2*4..c2*4+3
  int c0 = c2 * 4;
  const float* Wr = Wbig + 512 * 256 + c0;
  f32x2 w5A = *(const f32x2*)(Wr);        f32x2 w5B = *(const f32x2*)(Wr + 2);
  f32x2 a0A = *(const f32x2*)(Wr + 256);  f32x2 a0B = *(const f32x2*)(Wr + 258);
  f32x2 a1A = *(const f32x2*)(Wr + 512);  f32x2 a1B = *(const f32x2*)(Wr + 514);
  f32x2 a2A = *(const f32x2*)(Wr + 768);  f32x2 a2B = *(const f32x2*)(Wr + 770);
  f32x2 a3A = *(const f32x2*)(Wr + 1024); f32x2 a3B = *(const f32x2*)(Wr + 1026);
  f32x2 bbA = *(const f32x2*)(b1 + c0);   f32x2 bbB = *(const f32x2*)(b1 + c0 + 2);
  const uint* Pme = Pu + (uint)(offI + c2 * 2);
  const uint* Pmj = Pu + (uint)(offI + 128 + c2 * 2);
#pragma unroll 2
  for (int it = 0; it < 16; ++it) {
    int e = it * 4 + es;
    uint2 pi = *(const uint2*)(Pme + s_pio[e]);
    uint2 pj = *(const uint2*)(Pmj + s_pjo[e]);
    f32x2 d2v;
    d2v.x = s_d2[e];
    d2v.y = d2v.x;
    float4 av = s_a4[e];
    f32x2 vA = (f32x2){bflo(pi.x), bfhi(pi.x)} + (f32x2){bflo(pj.x), bfhi(pj.x)};
    f32x2 vB = (f32x2){bflo(pi.y), bfhi(pi.y)} + (f32x2){bflo(pj.y), bfhi(pj.y)};
    f32x2 axv = {av.x, av.x}, ayv = {av.y, av.y}, azv = {av.z, av.z}, awv = {av.w, av.w};
    f32x2 zA = bbA + d2v * w5A + axv * a0A + ayv * a1A + azv * a2A + awv * a3A;
    f32x2 zB = bbB + d2v * w5B + axv * a0B + ayv * a1B + azv * a2B + awv * a3B;
    vA = silu2(vA + zA);
    vB = silu2(vB + zB);
    uint2 o;
    o.x = cvtpk(vA.x, vA.y);
    o.y = cvtpk(vB.x, vB.y);
    *(uint2*)((char*)Ab + e * 512 + ((c0 * 2) ^ ((e & 7) << 4))) = o;
  }
}

// monolithic edge kernel (R5 phase structure, de-spilled buildT1)
__global__ __launch_bounds__(256, 4) void k_edge(
    const float* __restrict__ x, const int* __restrict__ eidx,
    const float* __restrict__ a, const float* __restrict__ emask,
    const uint* __restrict__ perm,
    const ushort* __restrict__ P, const ushort* __restrict__ WT,
    const float* __restrict__ We1, const float* __restrict__ be1,
    const float* __restrict__ be2, const float* __restrict__ Wa,
    const float* __restrict__ ba,
    const float* __restrict__ Wx1, const float* __restrict__ bx1,
    const float* __restrict__ bx2, const float* __restrict__ Wx3,
    ushort* __restrict__ em_agg, float* __restrict__ x_agg) {
  __shared__ ushort Ab[TE * 256];  // 32 KiB swizzled T1 tile / em staging
  __shared__ uint s_ij[TE];        // i4 | (j4<<16), sorted by i4
  __shared__ uint s_pio[TE], s_pjo[TE];  // P row offsets (uint idx)
  __shared__ float s_d2[TE];
  __shared__ float4 s_a4[TE];
  __shared__ float s_dx[TE], s_dy[TE], s_dz[TE];
  __shared__ float s_red[2][TE];
  __shared__ ushort s_seghead[TE + 2];
  __shared__ int s_nseg;
  int t = threadIdx.x;
  int bid = blockIdx.x;
  bid = (bid & 7) * 504 + (bid >> 3);  // XCD swizzle (4032 = 8*504)
  int ebase = bid * TE;                // sorted slots; one batch per block

  if (t < TE) {  // phase 0: edge meta (CSR-sorted gather) -- exactly wave 0
    int eid = (int)perm[ebase + t];
    int b = ebase / E_;
    int2 ij = *(const int2*)(eidx + (size_t)eid * 2);
    uint i4 = (uint)(b * 64 + ij.x);
    uint j4 = (uint)(b * 64 + ij.y);
    s_ij[t] = i4 | (j4 << 16);
    s_pio[t] = i4 * 640u;
    s_pjo[t] = j4 * 640u;
    float m = emask[eid];
    float dx = (x[i4 * 3 + 0] - x[j4 * 3 + 0]) * m;
    float dy = (x[i4 * 3 + 1] - x[j4 * 3 + 1]) * m;
    float dz = (x[i4 * 3 + 2] - x[j4 * 3 + 2]) * m;
    s_d2[t] = dx * dx + dy * dy + dz * dz;
    s_dx[t] = dx; s_dy[t] = dy; s_dz[t] = dz;
    s_a4[t] = *(const float4*)(a + (size_t)eid * 4);
    s_red[0][t] = 0.f;
    s_red[1][t] = 0.f;
    // segment heads via wave ballot (no serial scan)
    uint prev = __shfl_up(i4, 1);
    int flag = (t == 0) || (i4 != prev);
    unsigned long long mask = __ballot(flag);
    int rank = (int)__popcll(mask & ((1ull << t) - 1ull));
    if (flag) s_seghead[rank] = (ushort)t;
    if (t == 0) {
      int ns = (int)__popcll(mask);
      s_nseg = ns;
      s_seghead[ns] = TE;
    }
  }
  __syncthreads();

  const uint* Pu = (const uint*)P;
  int w = t >> 6, lane = t & 63, l15 = lane & 15, lhi = lane >> 4;
  float ba0 = ba[0];

  // ---- branch 1 first (x/Wx2): frees Ab for em staging at the end ----
  buildT1(t, Pu, Wx1, bx1, 256, Ab, s_pio, s_pjo, s_d2, s_a4);
  __syncthreads();
  {
    f32x4 acc1[4][4] = {};
    gemmT<4>(Ab, WT + 6 * 65536, w, l15, lhi, acc1);
    int colb = w * 64 + l15;
    f32x2 wvA = {Wx3[colb], Wx3[colb + 16]};
    f32x2 wvB = {Wx3[colb + 32], Wx3[colb + 48]};
    f32x2 b2A = {bx2[colb], bx2[colb + 16]};
    f32x2 b2B = {bx2[colb + 32], bx2[colb + 48]};
#pragma unroll
    for (int rm = 0; rm < 4; ++rm)
#pragma unroll
      for (int r = 0; r < 4; ++r) {
        f32x2 mA = silu2((f32x2){acc1[rm][0][r], acc1[rm][1][r]} + b2A);
        f32x2 mB = silu2((f32x2){acc1[rm][2][r], acc1[rm][3][r]} + b2B);
        f32x2 q = mA * wvA + mB * wvB;
        float p = q.x + q.y;
        p += __shfl_xor(p, 1);
        p += __shfl_xor(p, 2);
        p += __shfl_xor(p, 4);
        p += __shfl_xor(p, 8);
        if (l15 == 0) atomicAdd(&s_red[1][rm * 16 + lhi * 4 + r], p);
      }
  }
  __syncthreads();  // s_red[1] final; Ab free (gemm1 reads done)

  // ---- branch 0 build (h/We2) ----
  buildT1(t, Pu, We1, be1, 0, Ab, s_pio, s_pjo, s_d2, s_a4);
  __syncthreads();

  // ---- x_agg: wave-assigned segments, lane-parallel fac, overlaps gemm0 ----
  {
    int ns = s_nseg;
    for (int s = w; s < ns; s += 4) {
      int st = s_seghead[s], en = s_seghead[s + 1];
      int r = st + lane;
      float sx = 0.f, sy = 0.f, sz = 0.f;
      if (r < en) {
        float fac = tanh_(s_red[1][r]) * 15.0f * rcp_(sqrtf(s_d2[r]) + 1.0f);
        sx = fac * s_dx[r]; sy = fac * s_dy[r]; sz = fac * s_dz[r];
      }
#pragma unroll
      for (int d = 1; d < 64; d <<= 1) {
        sx += __shfl_xor(sx, d);
        sy += __shfl_xor(sy, d);
        sz += __shfl_xor(sz, d);
      }
      if (lane == 0) {
        uint i4 = s_ij[st] & 0xffffu;
        atomicAdd(x_agg + i4 * 3u + 0, sx);
        atomicAdd(x_agg + i4 * 3u + 1, sy);
        atomicAdd(x_agg + i4 * 3u + 2, sz);
      }
    }
  }

  // ---- branch 0 gemm + epilogue ----
  f32x4 acc0[4][4] = {};
  gemmT<4>(Ab, WT + 5 * 65536, w, l15, lhi, acc0);
  {
    int colb = w * 64 + l15;
    f32x2 wvA = {Wa[colb], Wa[colb + 16]};
    f32x2 wvB = {Wa[colb + 32], Wa[colb + 48]};
    f32x2 b2A = {be2[colb], be2[colb + 16]};
    f32x2 b2B = {be2[colb + 32], be2[colb + 48]};
#pragma unroll
    for (int rm = 0; rm < 4; ++rm)
#pragma unroll
      for (int r = 0; r < 4; ++r) {
        f32x2 mA = silu2((f32x2){acc0[rm][0][r], acc0[rm][1][r]} + b2A);
        f32x2 mB = silu2((f32x2){acc0[rm][2][r], acc0[rm][3][r]} + b2B);
        acc0[rm][0][r] = mA.x; acc0[rm][1][r] = mA.y;
        acc0[rm][2][r] = mB.x; acc0[rm][3][r] = mB.y;
        f32x2 q = mA * wvA + mB * wvB;
        float p = q.x + q.y;
        p += __shfl_xor(p, 1);
        p += __shfl_xor(p, 2);
        p += __shfl_xor(p, 4);
        p += __shfl_xor(p, 8);
        if (l15 == 0) atomicAdd(&s_red[0][rm * 16 + lhi * 4 + r], p);
      }
  }
  __syncthreads();  // s_red[0] final; Ab free (gemm0 reads done)

  // ---- gate (per-thread recompute: race-free, no extra barrier) + dump ----
  uint* AbU = (uint*)Ab;
#pragma unroll
  for (int rm = 0; rm < 4; ++rm)
#pragma unroll
    for (int r = 0; r < 4; ++r) {
      int row = rm * 16 + lhi * 4 + r;
      float g = sigmoid_(s_red[0][row] + ba0);
#pragma unroll
      for (int cn = 0; cn < 4; ++cn) {
        float vme = g * acc0[rm][cn][r];
        float vpo = __shfl_xor(vme, 1);
        if (!(l15 & 1)) {
          int cp = (w * 64 + cn * 16 + l15) >> 1;
          AbU[row * 128 + cp] = cvtpk(vme, vpo);
        }
      }
    }
  __syncthreads();

  // ---- segmented em reduction: fp32 sum over rows, 1 pk atomic per (seg,colpair)
  {
    int ns = s_nseg;
    int c = t & 127;
    for (int s = t >> 7; s < ns; s += 2) {
      int st = s_seghead[s], en = s_seghead[s + 1];
      f32x2 sum = {0.f, 0.f};
      for (int r = st; r < en; ++r) {
        uint u = AbU[r * 128 + c];
        sum += (f32x2){bflo(u), bfhi(u)};
      }
      uint i4 = s_ij[st] & 0xffffu;
      atom_pk_bf16(em_agg + i4 * 256u + (uint)(c * 2), cvtpk(sum.x, sum.y));
    }
  }
}

__global__ __launch_bounds__(256, 2) void k_node(
    const float* __restrict__ h, const float* __restrict__ x,
    const float* __restrict__ nmask,
    const ushort* __restrict__ em_agg, const float* __restrict__ x_agg,
    const ushort* __restrict__ P, const ushort* __restrict__ WT,
    const float* __restrict__ bh1, const float* __restrict__ bh2,
    float* __restrict__ out) {
  __shared__ ushort Ab[32 * 256];
  int t = threadIdx.x;
  int rowbase = blockIdx.x * 32;  // 128 blocks
  {  // stage em (bf16) into swizzled LDS
    const uint* emu = (const uint*)em_agg;
    int c2 = t & 127, es = t >> 7;
#pragma unroll 4
    for (int it = 0; it < 16; ++it) {
      int row = it * 2 + es;
      uint v = emu[(size_t)(rowbase + row) * 128 + c2];
      *(uint*)((char*)Ab + row * 512 + ((c2 * 4) ^ ((row & 7) << 4))) = v;
    }
  }
  __syncthreads();
  int w = t >> 6, lane = t & 63, l15 = lane & 15, lhi = lane >> 4;
  {
    f32x4 acc[2][4] = {};
    gemmT<2>(Ab, WT + 7 * 65536, w, l15, lhi, acc);  // em_agg @ Wh1bot
    __syncthreads();
    float bc[4];
#pragma unroll
    for (int cn = 0; cn < 4; ++cn) bc[cn] = bh1[w * 64 + cn * 16 + l15];
#pragma unroll
    for (int rm = 0; rm < 2; ++rm)
#pragma unroll
      for (int cn = 0; cn < 4; ++cn)
#pragma unroll
        for (int r = 0; r < 4; ++r) {
          int row = rm * 16 + lhi * 4 + r;
          int col = w * 64 + cn * 16 + l15;
          float q1 = bf2f(P[(size_t)(rowbase + row) * 1280 + 1024 + col]);  // h@Wh1top
          float sv = silu_(acc[rm][cn][r] + q1 + bc[cn]);
          *(ushort*)((char*)Ab + row * 512 + ((col * 2) ^ ((row & 7) << 4))) = f2bf(sv);
        }
  }
  __syncthreads();
  {
    f32x4 acc[2][4] = {};
    gemmT<2>(Ab, WT + 8 * 65536, w, l15, lhi, acc);  // silu(...) @ Wh2
    float bc[4];
#pragma unroll
    for (int cn = 0; cn < 4; ++cn) bc[cn] = bh2[w * 64 + cn * 16 + l15];
#pragma unroll
    for (int rm = 0; rm < 2; ++rm)
#pragma unroll
      for (int cn = 0; cn < 4; ++cn)
#pragma unroll
        for (int r = 0; r < 4; ++r) {
          int row = rowbase + rm * 16 + lhi * 4 + r;
          int col = w * 64 + cn * 16 + l15;
          float o = (h[(size_t)row * 256 + col] + acc[rm][cn][r] + bc[cn]) * nmask[row];
          out[12288 + (size_t)row * 256 + col] = o;
        }
  }
  if (t < 32) {  // x_out
    int row = rowbase + t;
    float nm = nmask[row];
#pragma unroll
    for (int c = 0; c < 3; ++c)
      out[row * 3 + c] = (x[row * 3 + c] + x_agg[row * 3 + c]) * nm;
  }
}

extern "C" void kernel_launch(void* const* d_in, const int* in_sizes, int n_in,
                              void* d_out, int out_size, void* d_ws, size_t ws_size,
                              hipStream_t stream) {
  (void)in_sizes; (void)n_in; (void)out_size; (void)ws_size;
  const float* x = (const float*)d_in[0];
  const float* h = (const float*)d_in[1];
  const float* a = (const float*)d_in[2];
  const int* eidx = (const int*)d_in[3];
  const float* nmask = (const float*)d_in[4];
  const float* emask = (const float*)d_in[5];
  const float* We1 = (const float*)d_in[6];
  const float* be1 = (const float*)d_in[7];
  const float* We2 = (const float*)d_in[8];
  const float* be2 = (const float*)d_in[9];
  const float* Wa = (const float*)d_in[10];
  const float* ba = (const float*)d_in[11];
  const float* Wh1 = (const float*)d_in[12];
  const float* bh1 = (const float*)d_in[13];
  const float* Wh2 = (const float*)d_in[14];
  const float* bh2 = (const float*)d_in[15];
  const float* Wx1 = (const float*)d_in[16];
  const float* bx1 = (const float*)d_in[17];
  const float* Wx2 = (const float*)d_in[18];
  const float* bx2 = (const float*)d_in[19];
  const float* Wx3 = (const float*)d_in[20];

  char* ws = (char*)d_ws;
  ushort* WT = (ushort*)ws;                   // 9*65536*2   = 1,179,648 B
  ushort* P = (ushort*)(ws + 1179648);        // 4096*1280*2 = 10,485,760 B
  ushort* em_agg = (ushort*)(ws + 11665408);  // 4096*256*2  = 2,097,152 B
  float* x_agg = (float*)(ws + 13762560);     // 4096*3*4    = 49,152 B
  uint* cnt = (uint*)(ws + 13811712);         // 4096*4      = 16,384 B
  uint* cursor = (uint*)(ws + 13828096);      // 4096*4      = 16,384 B
  uint* perm = (uint*)(ws + 13844480);        // 258048*4    = 1,032,192 B

  // zero em_agg + x_agg + cnt (contiguous)
  hipMemsetAsync(em_agg, 0, 2097152 + 49152 + 16384, stream);
  k_count_prep<<<1152, 256, 0, stream>>>(eidx, cnt, We1, Wx1, Wh1, We2, Wx2, Wh2, WT);
  k_scan<<<1, 256, 0, stream>>>(cnt, cursor);
  k_fill_proj<<<1168, 256, 0, stream>>>(eidx, cursor, perm, h, WT, P);
  k_edge<<<NB, 256, 0, stream>>>(x, eidx, a, emask, perm, P, WT, We1, be1, be2, Wa, ba,
                                 Wx1, bx1, bx2, Wx3, em_agg, x_agg);
  k_node<<<128, 256, 0, stream>>>(h, x, nmask, em_agg, x_agg, P, WT, bh1, bh2,
                                  (float*)d_out);
}

// Round 11
// 265.291 us; speedup vs baseline: 1.3866x; 1.0265x over previous
//
#include <hip/hip_runtime.h>

#define E_ 4032
#define TE 64
#define NB 4032  // 258048 / TE

typedef unsigned int uint;
typedef unsigned short ushort;
typedef __attribute__((ext_vector_type(8))) short short8;
typedef __attribute__((ext_vector_type(4))) float f32x4;
typedef __attribute__((ext_vector_type(2))) float f32x2;

__device__ __forceinline__ ushort f2bf(float x) {
  uint u = __float_as_uint(x);
  return (ushort)((u + 0x7fffu + ((u >> 16) & 1u)) >> 16);  // RNE f32->bf16
}
__device__ __forceinline__ uint cvtpk(float lo, float hi) {
  uint r;
  asm("v_cvt_pk_bf16_f32 %0, %1, %2" : "=v"(r) : "v"(lo), "v"(hi));
  return r;
}
__device__ __forceinline__ float exp2_(float x) {
  float r;
  asm("v_exp_f32 %0, %1" : "=v"(r) : "v"(x));
  return r;
}
__device__ __forceinline__ float bflo(uint u) { return __uint_as_float(u << 16); }
__device__ __forceinline__ float bfhi(uint u) { return __uint_as_float(u & 0xffff0000u); }
__device__ __forceinline__ float bf2f(ushort s) { return __uint_as_float((uint)s << 16); }
__device__ __forceinline__ float rcp_(float x) { return __builtin_amdgcn_rcpf(x); }
__device__ __forceinline__ float silu_(float v) { return v * rcp_(1.0f + exp2_(v * -1.44269504f)); }
__device__ __forceinline__ float sigmoid_(float v) { return rcp_(1.0f + exp2_(v * -1.44269504f)); }
__device__ __forceinline__ float tanh_(float v) { return 1.0f - 2.0f * rcp_(1.0f + exp2_(v * 2.88539008f)); }

__device__ __forceinline__ f32x2 silu2(f32x2 v) {
  f32x2 nm = v * (f32x2){-1.44269504f, -1.44269504f};
  f32x2 e = {exp2_(nm.x), exp2_(nm.y)};
  f32x2 den = e + (f32x2){1.0f, 1.0f};
  f32x2 r = {rcp_(den.x), rcp_(den.y)};
  return v * r;
}

__device__ __forceinline__ void atom_pk_bf16(ushort* p, uint v) {
  asm volatile("global_atomic_pk_add_bf16 %0, %1, off" :: "v"(p), "v"(v) : "memory");
}

// RM*16 x 256 (A, LDS, swizzled bf16) @ 256x256 (B = WT[n][k] bf16, L2) -> acc
// wave w owns cols [w*64, w*64+64)
template <int RM>
__device__ __forceinline__ void gemmT(const ushort* Ab, const ushort* Bmat,
                                      int w, int l15, int lhi, f32x4 acc[RM][4]) {
#pragma unroll
  for (int ks = 0; ks < 8; ++ks) {
    short8 bv[4];
#pragma unroll
    for (int cn = 0; cn < 4; ++cn) {
      int col = w * 64 + cn * 16 + l15;
      bv[cn] = *(const short8*)(Bmat + col * 256 + ks * 32 + lhi * 8);
    }
    short8 av[RM];
#pragma unroll
    for (int rm = 0; rm < RM; ++rm) {
      int row = rm * 16 + l15;
      int byt = (ks * 64 + lhi * 16) ^ ((row & 7) << 4);
      av[rm] = *(const short8*)((const char*)Ab + row * 512 + byt);
    }
#pragma unroll
    for (int cn = 0; cn < 4; ++cn)
#pragma unroll
      for (int rm = 0; rm < RM; ++rm)
        acc[rm][cn] = __builtin_amdgcn_mfma_f32_16x16x32_bf16(av[rm], bv[cn], acc[rm][cn], 0, 0, 0);
  }
}

// ---- fused: CSR count (1008) + weight prep (144) + agg zeroing (131) ----
// WT[9][256][256] bf16, WT[m][n][k] = srcm[k*256 + n]
__global__ __launch_bounds__(256) void k_count_prep(
    const int* __restrict__ eidx, uint* __restrict__ cnt,
    const float* __restrict__ We1, const float* __restrict__ Wx1,
    const float* __restrict__ Wh1, const float* __restrict__ We2,
    const float* __restrict__ Wx2, const float* __restrict__ Wh2,
    ushort* __restrict__ WT, uint4* __restrict__ zbase) {
  __shared__ float tl[64][65];
  int bid = blockIdx.x;
  int t = threadIdx.x;
  if (bid < 1008) {
    int g = bid * 256 + t;
    int b = g / E_;
    int i = eidx[(size_t)g * 2];
    atomicAdd(&cnt[b * 64 + i], 1u);
    return;
  }
  if (bid >= 1152) {  // zero em_agg + x_agg: 131 blocks * 256 thr * 64 B = 2,146,304 B
    uint4* z = zbase + (size_t)((bid - 1152) * 256 + t) * 4;
    uint4 zz = {0u, 0u, 0u, 0u};
    z[0] = zz; z[1] = zz; z[2] = zz; z[3] = zz;
    return;
  }
  int blk = bid - 1008;
  int m = blk >> 4, tile = blk & 15;
  int kt = (tile & 3) * 64, nt = (tile >> 2) * 64;
  const float* src;
  switch (m) {
    case 0: src = We1; break;
    case 1: src = We1 + 65536; break;
    case 2: src = Wx1; break;
    case 3: src = Wx1 + 65536; break;
    case 4: src = Wh1; break;
    case 5: src = We2; break;
    case 6: src = Wx2; break;
    case 7: src = Wh1 + 65536; break;
    default: src = Wh2; break;
  }
  int c = t & 63, r4 = t >> 6;
#pragma unroll
  for (int rr = 0; rr < 64; rr += 4)
    tl[rr + r4][c] = src[(size_t)(kt + rr + r4) * 256 + nt + c];
  __syncthreads();
#pragma unroll
  for (int rr = 0; rr < 64; rr += 4)
    WT[(size_t)m * 65536 + (size_t)(nt + rr + r4) * 256 + kt + c] = f2bf(tl[c][rr + r4]);
}

__global__ __launch_bounds__(256) void k_scan(const uint* __restrict__ cnt,
                                              uint* __restrict__ cursor) {
  __shared__ uint sw[4];
  int t = threadIdx.x;
  uint loc[16];
  uint tot = 0;
#pragma unroll
  for (int q = 0; q < 16; ++q) {
    loc[q] = cnt[t * 16 + q];
    tot += loc[q];
  }
  uint v = tot;  // inclusive scan within wave
#pragma unroll
  for (int d = 1; d < 64; d <<= 1) {
    uint u = __shfl_up(v, d);
    if ((t & 63) >= d) v += u;
  }
  if ((t & 63) == 63) sw[t >> 6] = v;
  __syncthreads();
  uint woff = 0;
  int wv = t >> 6;
  if (wv > 0) woff += sw[0];
  if (wv > 1) woff += sw[1];
  if (wv > 2) woff += sw[2];
  uint run = woff + v - tot;  // global exclusive prefix
#pragma unroll
  for (int q = 0; q < 16; ++q) {
    cursor[t * 16 + q] = run;
    run += loc[q];
  }
}

// ---- fused: CSR fill (1008 blocks) + projection GEMM (160 blocks) ----
// P[4096][1280] bf16 = h @ [We1L|We1R|Wx1L|Wx1R|Wh1top]
__global__ __launch_bounds__(256, 2) void k_fill_proj(
    const int* __restrict__ eidx, uint* __restrict__ cursor,
    uint* __restrict__ perm, const float* __restrict__ h,
    const ushort* __restrict__ WT, ushort* __restrict__ P) {
  __shared__ ushort Ab[128 * 256];
  int bid = blockIdx.x;
  int t = threadIdx.x;
  if (bid < 1008) {
    int g = bid * 256 + t;
    int b = g / E_;
    int i = eidx[(size_t)g * 2];
    uint slot = atomicAdd(&cursor[b * 64 + i], 1u);
    perm[slot] = (uint)g;
    return;
  }
  int blk = bid - 1008;
  int rowbase = (blk & 31) * 128;
  int g = blk >> 5;  // 0..4
  {
    int c2 = t & 127, es = t >> 7;
#pragma unroll 4
    for (int it = 0; it < 64; ++it) {
      int row = it * 2 + es;
      float2 v = *(const float2*)(h + (size_t)(rowbase + row) * 256 + c2 * 2);
      *(uint*)((char*)Ab + row * 512 + ((c2 * 4) ^ ((row & 7) << 4))) = cvtpk(v.x, v.y);
    }
  }
  __syncthreads();
  int w = t >> 6, lane = t & 63, l15 = lane & 15, lhi = lane >> 4;
  f32x4 acc[8][4] = {};
  gemmT<8>(Ab, WT + g * 65536, w, l15, lhi, acc);
#pragma unroll
  for (int rm = 0; rm < 8; ++rm)
#pragma unroll
    for (int cn = 0; cn < 4; ++cn)
#pragma unroll
      for (int r = 0; r < 4; ++r) {
        int row = rowbase + rm * 16 + lhi * 4 + r;
        int col = w * 64 + cn * 16 + l15;
        P[(size_t)row * 1280 + g * 256 + col] = f2bf(acc[rm][cn][r]);
      }
}

// build T1 = silu(P_i + P_j + d2*w512 + a@Wrows + b1) into swizzled LDS tile
// unroll 2 (NOT full): keeps in-flight gather state at 4 uint2 -> no scratch
// spill (R4: FETCH 18.7MB; R5 full-unroll: FETCH 61MB, WRITE +70MB scratch).
__device__ __forceinline__ void buildT1(int t, const uint* __restrict__ Pu,
                                        const float* __restrict__ Wbig,
                                        const float* __restrict__ b1, int offI,
                                        ushort* Ab, const uint* s_pio,
                                        const uint* s_pjo,
                                        const float* s_d2, const float4* s_a4) {
  int c2 = t & 63, es = t >> 6;  // c2: uint2 index -> cols c2*4..c2*4+3
  int c0 = c2 * 4;
  const float* Wr = Wbig + 512 * 256 + c0;
  f32x2 w5A = *(const f32x2*)(Wr);        f32x2 w5B = *(const f32x2*)(Wr + 2);
  f32x2 a0A = *(const f32x2*)(Wr + 256);  f32x2 a0B = *(const f32x2*)(Wr + 258);
  f32x2 a1A = *(const f32x2*)(Wr + 512);  f32x2 a1B = *(const f32x2*)(Wr + 514);
  f32x2 a2A = *(const f32x2*)(Wr + 768);  f32x2 a2B = *(const f32x2*)(Wr + 770);
  f32x2 a3A = *(const f32x2*)(Wr + 1024); f32x2 a3B = *(const f32x2*)(Wr + 1026);
  f32x2 bbA = *(const f32x2*)(b1 + c0);   f32x2 bbB = *(const f32x2*)(b1 + c0 + 2);
  const uint* Pme = Pu + (uint)(offI + c2 * 2);
  const uint* Pmj = Pu + (uint)(offI + 128 + c2 * 2);
#pragma unroll 2
  for (int it = 0; it < 16; ++it) {
    int e = it * 4 + es;
    uint2 pi = *(const uint2*)(Pme + s_pio[e]);
    uint2 pj = *(const uint2*)(Pmj + s_pjo[e]);
    f32x2 d2v;
    d2v.x = s_d2[e];
    d2v.y = d2v.x;
    float4 av = s_a4[e];
    f32x2 vA = (f32x2){bflo(pi.x), bfhi(pi.x)} + (f32x2){bflo(pj.x), bfhi(pj.x)};
    f32x2 vB = (f32x2){bflo(pi.y), bfhi(pi.y)} + (f32x2){bflo(pj.y), bfhi(pj.y)};
    f32x2 axv = {av.x, av.x}, ayv = {av.y, av.y}, azv = {av.z, av.z}, awv = {av.w, av.w};
    f32x2 zA = bbA + d2v * w5A + axv * a0A + ayv * a1A + azv * a2A + awv * a3A;
    f32x2 zB = bbB + d2v * w5B + axv * a0B + ayv * a1B + azv * a2B + awv * a3B;
    vA = silu2(vA + zA);
    vB = silu2(vB + zB);
    uint2 o;
    o.x = cvtpk(vA.x, vA.y);
    o.y = cvtpk(vB.x, vB.y);
    *(uint2*)((char*)Ab + e * 512 + ((c0 * 2) ^ ((e & 7) << 4))) = o;
  }
}

// monolithic edge kernel (R10 structure + setprio around GEMMs)
__global__ __launch_bounds__(256, 4) void k_edge(
    const float* __restrict__ x, const int* __restrict__ eidx,
    const float* __restrict__ a, const float* __restrict__ emask,
    const uint* __restrict__ perm,
    const ushort* __restrict__ P, const ushort* __restrict__ WT,
    const float* __restrict__ We1, const float* __restrict__ be1,
    const float* __restrict__ be2, const float* __restrict__ Wa,
    const float* __restrict__ ba,
    const float* __restrict__ Wx1, const float* __restrict__ bx1,
    const float* __restrict__ bx2, const float* __restrict__ Wx3,
    ushort* __restrict__ em_agg, float* __restrict__ x_agg) {
  __shared__ ushort Ab[TE * 256];  // 32 KiB swizzled T1 tile / em staging
  __shared__ uint s_ij[TE];        // i4 | (j4<<16), sorted by i4
  __shared__ uint s_pio[TE], s_pjo[TE];  // P row offsets (uint idx)
  __shared__ float s_d2[TE];
  __shared__ float4 s_a4[TE];
  __shared__ float s_dx[TE], s_dy[TE], s_dz[TE];
  __shared__ float s_red[2][TE];
  __shared__ ushort s_seghead[TE + 2];
  __shared__ int s_nseg;
  int t = threadIdx.x;
  int bid = blockIdx.x;
  bid = (bid & 7) * 504 + (bid >> 3);  // XCD swizzle (4032 = 8*504)
  int ebase = bid * TE;                // sorted slots; one batch per block

  if (t < TE) {  // phase 0: edge meta (CSR-sorted gather) -- exactly wave 0
    int eid = (int)perm[ebase + t];
    int b = ebase / E_;
    int2 ij = *(const int2*)(eidx + (size_t)eid * 2);
    uint i4 = (uint)(b * 64 + ij.x);
    uint j4 = (uint)(b * 64 + ij.y);
    s_ij[t] = i4 | (j4 << 16);
    s_pio[t] = i4 * 640u;
    s_pjo[t] = j4 * 640u;
    float m = emask[eid];
    float dx = (x[i4 * 3 + 0] - x[j4 * 3 + 0]) * m;
    float dy = (x[i4 * 3 + 1] - x[j4 * 3 + 1]) * m;
    float dz = (x[i4 * 3 + 2] - x[j4 * 3 + 2]) * m;
    s_d2[t] = dx * dx + dy * dy + dz * dz;
    s_dx[t] = dx; s_dy[t] = dy; s_dz[t] = dz;
    s_a4[t] = *(const float4*)(a + (size_t)eid * 4);
    s_red[0][t] = 0.f;
    s_red[1][t] = 0.f;
    // segment heads via wave ballot (no serial scan)
    uint prev = __shfl_up(i4, 1);
    int flag = (t == 0) || (i4 != prev);
    unsigned long long mask = __ballot(flag);
    int rank = (int)__popcll(mask & ((1ull << t) - 1ull));
    if (flag) s_seghead[rank] = (ushort)t;
    if (t == 0) {
      int ns = (int)__popcll(mask);
      s_nseg = ns;
      s_seghead[ns] = TE;
    }
  }
  __syncthreads();

  const uint* Pu = (const uint*)P;
  int w = t >> 6, lane = t & 63, l15 = lane & 15, lhi = lane >> 4;
  float ba0 = ba[0];

  // ---- branch 1 first (x/Wx2): frees Ab for em staging at the end ----
  buildT1(t, Pu, Wx1, bx1, 256, Ab, s_pio, s_pjo, s_d2, s_a4);
  __syncthreads();
  {
    f32x4 acc1[4][4] = {};
    __builtin_amdgcn_s_setprio(1);
    gemmT<4>(Ab, WT + 6 * 65536, w, l15, lhi, acc1);
    __builtin_amdgcn_s_setprio(0);
    int colb = w * 64 + l15;
    f32x2 wvA = {Wx3[colb], Wx3[colb + 16]};
    f32x2 wvB = {Wx3[colb + 32], Wx3[colb + 48]};
    f32x2 b2A = {bx2[colb], bx2[colb + 16]};
    f32x2 b2B = {bx2[colb + 32], bx2[colb + 48]};
#pragma unroll
    for (int rm = 0; rm < 4; ++rm)
#pragma unroll
      for (int r = 0; r < 4; ++r) {
        f32x2 mA = silu2((f32x2){acc1[rm][0][r], acc1[rm][1][r]} + b2A);
        f32x2 mB = silu2((f32x2){acc1[rm][2][r], acc1[rm][3][r]} + b2B);
        f32x2 q = mA * wvA + mB * wvB;
        float p = q.x + q.y;
        p += __shfl_xor(p, 1);
        p += __shfl_xor(p, 2);
        p += __shfl_xor(p, 4);
        p += __shfl_xor(p, 8);
        if (l15 == 0) atomicAdd(&s_red[1][rm * 16 + lhi * 4 + r], p);
      }
  }
  __syncthreads();  // s_red[1] final; Ab free (gemm1 reads done)

  // ---- branch 0 build (h/We2) ----
  buildT1(t, Pu, We1, be1, 0, Ab, s_pio, s_pjo, s_d2, s_a4);
  __syncthreads();

  // ---- x_agg: wave-assigned segments, lane-parallel fac, overlaps gemm0 ----
  {
    int ns = s_nseg;
    for (int s = w; s < ns; s += 4) {
      int st = s_seghead[s], en = s_seghead[s + 1];
      int r = st + lane;
      float sx = 0.f, sy = 0.f, sz = 0.f;
      if (r < en) {
        float fac = tanh_(s_red[1][r]) * 15.0f * rcp_(sqrtf(s_d2[r]) + 1.0f);
        sx = fac * s_dx[r]; sy = fac * s_dy[r]; sz = fac * s_dz[r];
      }
#pragma unroll
      for (int d = 1; d < 64; d <<= 1) {
        sx += __shfl_xor(sx, d);
        sy += __shfl_xor(sy, d);
        sz += __shfl_xor(sz, d);
      }
      if (lane == 0) {
        uint i4 = s_ij[st] & 0xffffu;
        atomicAdd(x_agg + i4 * 3u + 0, sx);
        atomicAdd(x_agg + i4 * 3u + 1, sy);
        atomicAdd(x_agg + i4 * 3u + 2, sz);
      }
    }
  }

  // ---- branch 0 gemm + epilogue ----
  f32x4 acc0[4][4] = {};
  __builtin_amdgcn_s_setprio(1);
  gemmT<4>(Ab, WT + 5 * 65536, w, l15, lhi, acc0);
  __builtin_amdgcn_s_setprio(0);
  {
    int colb = w * 64 + l15;
    f32x2 wvA = {Wa[colb], Wa[colb + 16]};
    f32x2 wvB = {Wa[colb + 32], Wa[colb + 48]};
    f32x2 b2A = {be2[colb], be2[colb + 16]};
    f32x2 b2B = {be2[colb + 32], be2[colb + 48]};
#pragma unroll
    for (int rm = 0; rm < 4; ++rm)
#pragma unroll
      for (int r = 0; r < 4; ++r) {
        f32x2 mA = silu2((f32x2){acc0[rm][0][r], acc0[rm][1][r]} + b2A);
        f32x2 mB = silu2((f32x2){acc0[rm][2][r], acc0[rm][3][r]} + b2B);
        acc0[rm][0][r] = mA.x; acc0[rm][1][r] = mA.y;
        acc0[rm][2][r] = mB.x; acc0[rm][3][r] = mB.y;
        f32x2 q = mA * wvA + mB * wvB;
        float p = q.x + q.y;
        p += __shfl_xor(p, 1);
        p += __shfl_xor(p, 2);
        p += __shfl_xor(p, 4);
        p += __shfl_xor(p, 8);
        if (l15 == 0) atomicAdd(&s_red[0][rm * 16 + lhi * 4 + r], p);
      }
  }
  __syncthreads();  // s_red[0] final; Ab free (gemm0 reads done)

  // ---- gate (per-thread recompute: race-free, no extra barrier) + dump ----
  uint* AbU = (uint*)Ab;
#pragma unroll
  for (int rm = 0; rm < 4; ++rm)
#pragma unroll
    for (int r = 0; r < 4; ++r) {
      int row = rm * 16 + lhi * 4 + r;
      float g = sigmoid_(s_red[0][row] + ba0);
#pragma unroll
      for (int cn = 0; cn < 4; ++cn) {
        float vme = g * acc0[rm][cn][r];
        float vpo = __shfl_xor(vme, 1);
        if (!(l15 & 1)) {
          int cp = (w * 64 + cn * 16 + l15) >> 1;
          AbU[row * 128 + cp] = cvtpk(vme, vpo);
        }
      }
    }
  __syncthreads();

  // ---- segmented em reduction: fp32 sum over rows, 1 pk atomic per (seg,colpair)
  {
    int ns = s_nseg;
    int c = t & 127;
    for (int s = t >> 7; s < ns; s += 2) {
      int st = s_seghead[s], en = s_seghead[s + 1];
      f32x2 sum = {0.f, 0.f};
      for (int r = st; r < en; ++r) {
        uint u = AbU[r * 128 + c];
        sum += (f32x2){bflo(u), bfhi(u)};
      }
      uint i4 = s_ij[st] & 0xffffu;
      atom_pk_bf16(em_agg + i4 * 256u + (uint)(c * 2), cvtpk(sum.x, sum.y));
    }
  }
}

__global__ __launch_bounds__(256, 2) void k_node(
    const float* __restrict__ h, const float* __restrict__ x,
    const float* __restrict__ nmask,
    const ushort* __restrict__ em_agg, const float* __restrict__ x_agg,
    const ushort* __restrict__ P, const ushort* __restrict__ WT,
    const float* __restrict__ bh1, const float* __restrict__ bh2,
    float* __restrict__ out) {
  __shared__ ushort Ab[32 * 256];
  int t = threadIdx.x;
  int rowbase = blockIdx.x * 32;  // 128 blocks
  {  // stage em (bf16) into swizzled LDS
    const uint* emu = (const uint*)em_agg;
    int c2 = t & 127, es = t >> 7;
#pragma unroll 4
    for (int it = 0; it < 16; ++it) {
      int row = it * 2 + es;
      uint v = emu[(size_t)(rowbase + row) * 128 + c2];
      *(uint*)((char*)Ab + row * 512 + ((c2 * 4) ^ ((row & 7) << 4))) = v;
    }
  }
  __syncthreads();
  int w = t >> 6, lane = t & 63, l15 = lane & 15, lhi = lane >> 4;
  {
    f32x4 acc[2][4] = {};
    gemmT<2>(Ab, WT + 7 * 65536, w, l15, lhi, acc);  // em_agg @ Wh1bot
    __syncthreads();
    float bc[4];
#pragma unroll
    for (int cn = 0; cn < 4; ++cn) bc[cn] = bh1[w * 64 + cn * 16 + l15];
#pragma unroll
    for (int rm = 0; rm < 2; ++rm)
#pragma unroll
      for (int cn = 0; cn < 4; ++cn)
#pragma unroll
        for (int r = 0; r < 4; ++r) {
          int row = rm * 16 + lhi * 4 + r;
          int col = w * 64 + cn * 16 + l15;
          float q1 = bf2f(P[(size_t)(rowbase + row) * 1280 + 1024 + col]);  // h@Wh1top
          float sv = silu_(acc[rm][cn][r] + q1 + bc[cn]);
          *(ushort*)((char*)Ab + row * 512 + ((col * 2) ^ ((row & 7) << 4))) = f2bf(sv);
        }
  }
  __syncthreads();
  {
    f32x4 acc[2][4] = {};
    gemmT<2>(Ab, WT + 8 * 65536, w, l15, lhi, acc);  // silu(...) @ Wh2
    float bc[4];
#pragma unroll
    for (int cn = 0; cn < 4; ++cn) bc[cn] = bh2[w * 64 + cn * 16 + l15];
#pragma unroll
    for (int rm = 0; rm < 2; ++rm)
#pragma unroll
      for (int cn = 0; cn < 4; ++cn)
#pragma unroll
        for (int r = 0; r < 4; ++r) {
          int row = rowbase + rm * 16 + lhi * 4 + r;
          int col = w * 64 + cn * 16 + l15;
          float o = (h[(size_t)row * 256 + col] + acc[rm][cn][r] + bc[cn]) * nmask[row];
          out[12288 + (size_t)row * 256 + col] = o;
        }
  }
  if (t < 32) {  // x_out
    int row = rowbase + t;
    float nm = nmask[row];
#pragma unroll
    for (int c = 0; c < 3; ++c)
      out[row * 3 + c] = (x[row * 3 + c] + x_agg[row * 3 + c]) * nm;
  }
}

extern "C" void kernel_launch(void* const* d_in, const int* in_sizes, int n_in,
                              void* d_out, int out_size, void* d_ws, size_t ws_size,
                              hipStream_t stream) {
  (void)in_sizes; (void)n_in; (void)out_size; (void)ws_size;
  const float* x = (const float*)d_in[0];
  const float* h = (const float*)d_in[1];
  const float* a = (const float*)d_in[2];
  const int* eidx = (const int*)d_in[3];
  const float* nmask = (const float*)d_in[4];
  const float* emask = (const float*)d_in[5];
  const float* We1 = (const float*)d_in[6];
  const float* be1 = (const float*)d_in[7];
  const float* We2 = (const float*)d_in[8];
  const float* be2 = (const float*)d_in[9];
  const float* Wa = (const float*)d_in[10];
  const float* ba = (const float*)d_in[11];
  const float* Wh1 = (const float*)d_in[12];
  const float* bh1 = (const float*)d_in[13];
  const float* Wh2 = (const float*)d_in[14];
  const float* bh2 = (const float*)d_in[15];
  const float* Wx1 = (const float*)d_in[16];
  const float* bx1 = (const float*)d_in[17];
  const float* Wx2 = (const float*)d_in[18];
  const float* bx2 = (const float*)d_in[19];
  const float* Wx3 = (const float*)d_in[20];

  char* ws = (char*)d_ws;
  ushort* WT = (ushort*)ws;                   // 9*65536*2   = 1,179,648 B
  ushort* P = (ushort*)(ws + 1179648);        // 4096*1280*2 = 10,485,760 B
  ushort* em_agg = (ushort*)(ws + 11665408);  // 4096*256*2  = 2,097,152 B
  float* x_agg = (float*)(ws + 13762560);     // 4096*3*4    = 49,152 B
  uint* cnt = (uint*)(ws + 13811712);         // 4096*4      = 16,384 B
  uint* cursor = (uint*)(ws + 13828096);      // 4096*4      = 16,384 B
  uint* perm = (uint*)(ws + 13844480);        // 258048*4    = 1,032,192 B

  // cnt must be zero before k_count_prep's own atomics -> external memset;
  // em_agg/x_agg zeroed inside k_count_prep (consumed only by k_edge, later).
  hipMemsetAsync(cnt, 0, 16384, stream);
  k_count_prep<<<1283, 256, 0, stream>>>(eidx, cnt, We1, Wx1, Wh1, We2, Wx2, Wh2,
                                         WT, (uint4*)em_agg);
  k_scan<<<1, 256, 0, stream>>>(cnt, cursor);
  k_fill_proj<<<1168, 256, 0, stream>>>(eidx, cursor, perm, h, WT, P);
  k_edge<<<NB, 256, 0, stream>>>(x, eidx, a, emask, perm, P, WT, We1, be1, be2, Wa, ba,
                                 Wx1, bx1, bx2, Wx3, em_agg, x_agg);
  k_node<<<128, 256, 0, stream>>>(h, x, nmask, em_agg, x_agg, P, WT, bh1, bh2,
                                  (float*)d_out);
}